// Round 1
// 462.559 us; speedup vs baseline: 1.0012x; 1.0012x over previous
//
#include <hip/hip_runtime.h>
#include <hip/hip_fp16.h>
#include <math.h>

#define NN 10000
#define NE 160000
#define CH 128
#define SCALE_F 0.0625f
#define EPS_F 1.1920929e-07f

// bf16 helpers (RNE rounding)
__device__ __forceinline__ unsigned short f2bf(float x) {
    unsigned int u = __float_as_uint(x);
    u += 0x7FFFu + ((u >> 16) & 1u);
    return (unsigned short)(u >> 16);
}
__device__ __forceinline__ unsigned int pack2bf(float a, float b) {
    return (unsigned int)f2bf(a) | ((unsigned int)f2bf(b) << 16);
}
__device__ __forceinline__ float bf_lo(unsigned int u) { return __uint_as_float(u << 16); }
__device__ __forceinline__ float bf_hi(unsigned int u) { return __uint_as_float(u & 0xFFFF0000u); }

// non-temporal float4 load (rbf is read exactly once -> don't pollute L2/L3,
// keep them resident for the rec gather)
typedef float f4v __attribute__((ext_vector_type(4)));
__device__ __forceinline__ float4 ntload4(const float* p) {
    f4v t = __builtin_nontemporal_load((const f4v*)p);
    return make_float4(t.x, t.y, t.z, t.w);
}

// ---------------------------------------------------------------------------
// Detect int64-vs-int32 edge_index layout (block 0) + zero counts.
// ---------------------------------------------------------------------------
__global__ __launch_bounds__(256) void detect_zero_kernel(const int* __restrict__ ei,
                                                          int* __restrict__ flag,
                                                          int* __restrict__ counts) {
    int t = blockIdx.x * 256 + threadIdx.x;
    if (t < NN) counts[t] = 0;
    if (blockIdx.x == 0 && threadIdx.x < 64) {
        int val = ei[2 * threadIdx.x + 1];   // high words if int64; random indices if int32
        unsigned long long b = __ballot(val != 0);
        if (threadIdx.x == 0) *flag = (b == 0ULL) ? 1 : 0;
    }
}

// ---------------------------------------------------------------------------
// Weight transpose: w1t[c][d]=w1[d][c] (128x128), w2t[c][d]=w2[d][c] (128x384).
// ---------------------------------------------------------------------------
__global__ __launch_bounds__(256) void transpose_w_kernel(const float* __restrict__ w1,
                                                          const float* __restrict__ w2,
                                                          float* __restrict__ w1t,
                                                          float* __restrict__ w2t) {
    int idx = blockIdx.x * 256 + threadIdx.x;   // 0 .. 65535
    if (idx < 128 * 128) {
        int c = idx >> 7, d = idx & 127;
        w1t[c * 128 + d] = w1[d * 128 + c];
    } else {
        int o = idx - 128 * 128;                // 0 .. 49151
        int c = o / 384, d = o - c * 384;
        w2t[c * 384 + d] = w2[d * 128 + c];
    }
}

__global__ __launch_bounds__(256) void count_kernel(const int* __restrict__ ei,
                                                    const int* __restrict__ flag,
                                                    int* __restrict__ counts) {
    int e = blockIdx.x * 256 + threadIdx.x;
    if (e >= NE) return;
    int i = (*flag) ? ei[2 * (size_t)e] : ei[e];
    atomicAdd(&counts[i], 1);
}

// Single-block exclusive scan over NN counts -> offsets (and cursor copy).
__global__ __launch_bounds__(1024) void scan_kernel(const int* __restrict__ counts,
                                                    int* __restrict__ offsets,
                                                    int* __restrict__ cursor) {
    __shared__ int sm[1024];
    const int t = threadIdx.x;
    const int base = t * 10;                 // 1024*10 = 10240 >= NN
    int vals[10];
    int lsum = 0;
    #pragma unroll
    for (int k = 0; k < 10; ++k) {
        int idx = base + k;
        int v = (idx < NN) ? counts[idx] : 0;
        vals[k] = v;
        lsum += v;
    }
    sm[t] = lsum;
    __syncthreads();
    #pragma unroll
    for (int off = 1; off < 1024; off <<= 1) {
        int add = (t >= off) ? sm[t - off] : 0;
        __syncthreads();
        sm[t] += add;
        __syncthreads();
    }
    int run = sm[t] - lsum;
    #pragma unroll
    for (int k = 0; k < 10; ++k) {
        int idx = base + k;
        if (idx < NN) { offsets[idx] = run; cursor[idx] = run; }
        run += vals[k];
    }
}

// Bucket entry: {e, j, half2(ev0,ev1), half(ev2)} packed into int4 (16 B).
__global__ __launch_bounds__(256) void bucket_kernel(const int* __restrict__ ei,
                                                     const int* __restrict__ flag,
                                                     const float* __restrict__ ev,
                                                     int* __restrict__ cursor,
                                                     int4* __restrict__ bucket) {
    int e = blockIdx.x * 256 + threadIdx.x;
    if (e >= NE) return;
    int i, j;
    if (*flag) {
        i = ei[2 * (size_t)e];
        j = ei[2 * ((size_t)NE + e)];
    } else {
        i = ei[e];
        j = ei[NE + e];
    }
    float e0 = ev[(size_t)e * 3 + 0];
    float e1 = ev[(size_t)e * 3 + 1];
    float e2 = ev[(size_t)e * 3 + 2];
    __half2 h01 = __floats2half2_rn(e0, e1);
    __half  h2v = __float2half_rn(e2);
    unsigned int u01 = *reinterpret_cast<unsigned int*>(&h01);
    unsigned int u2  = (unsigned int)(*reinterpret_cast<unsigned short*>(&h2v));
    int pos = atomicAdd(&cursor[i], 1);
    bucket[pos] = make_int4(e, j, (int)u01, (int)u2);
}

// ---------------------------------------------------------------------------
// phi kernel (transposed-weight, output-stationary).
// NEW rec layout: per node, 32 channel-groups x 12 uints (48 B):
//   group cg (channels 4cg..4cg+3), uint offsets within group:
//     [0,1]   phi_s   (2x bf16 pairs)
//     [2,3]   phi_vv
//     [4,5]   phi_vs
//     [6,7]   v row 0
//     [8,9]   v row 1
//     [10,11] v row 2
// -> gather lane q reads its whole 48 B slice with 3x dwordx4.
// ---------------------------------------------------------------------------
__global__ __launch_bounds__(128) void phi_kernel(const float* __restrict__ s,
                                                  const float* __restrict__ v,
                                                  const float* __restrict__ w1t,
                                                  const float* __restrict__ b1,
                                                  const float* __restrict__ w2t,
                                                  const float* __restrict__ b2,
                                                  const float* __restrict__ rms_w,
                                                  unsigned int* __restrict__ rec) {
    __shared__ float xw[2][8][128];
    __shared__ float hh[2][8][128];

    const int t = threadIdx.x;      // 0..127
    const int wv = t >> 6;          // wave 0/1
    const int l = t & 63;
    const int half = l >> 5;        // c-parity half
    const int q = l & 31;           // output-channel group
    const int nbase = blockIdx.x * 16 + wv * 8;

    // --- Pack v into rec (independent of the MLP pipeline) ---
    {
        const int cg = l >> 1;              // channel group
        const int u  = l & 1;               // which uint within the pair
        #pragma unroll
        for (int nn = 0; nn < 8; ++nn) {
            const int gn = nbase + nn;
            const float2* vsrc = (const float2*)(v + (size_t)gn * 384);
            unsigned int* vdst = rec + (size_t)gn * 384 + cg * 12 + 6 + u;
            #pragma unroll
            for (int k = 0; k < 3; ++k) {
                float2 a = vsrc[k * 64 + l];            // channels 2l,2l+1 of row k
                vdst[2 * k] = pack2bf(a.x, a.y);
            }
        }
    }

    // --- RMSNorm: each half-wave handles 4 nodes, 32 lanes x float4 ---
    {
        const float4 rw = ((const float4*)rms_w)[q];
        #pragma unroll
        for (int r = 0; r < 4; ++r) {
            const int n = half * 4 + r;
            const int gn = nbase + n;
            float4 sv = ((const float4*)(s + (size_t)gn * CH))[q];
            float ss = sv.x * sv.x + sv.y * sv.y + sv.z * sv.z + sv.w * sv.w;
            #pragma unroll
            for (int off = 16; off > 0; off >>= 1) ss += __shfl_xor(ss, off, 32);
            const float sc = rsqrtf(ss * (1.0f / CH) + EPS_F);
            float4 o;
            o.x = sv.x * sc * rw.x;
            o.y = sv.y * sc * rw.y;
            o.z = sv.z * sc * rw.z;
            o.w = sv.w * sc * rw.w;
            *(float4*)&xw[wv][n][q * 4] = o;
        }
    }
    __syncthreads();

    // --- Phase 1: h = silu(x @ w1t + b1); halves split c, coalesced weights ---
    {
        float4 acc[8];
        const float4 bia = ((const float4*)b1)[q];
        #pragma unroll
        for (int n = 0; n < 8; ++n)
            acc[n] = (half == 0) ? bia : make_float4(0.f, 0.f, 0.f, 0.f);

        #pragma unroll 4
        for (int it = 0; it < 64; ++it) {
            const int c = 2 * it + half;
            const float4 w = *(const float4*)(w1t + (size_t)c * 128 + 4 * q);
            #pragma unroll
            for (int n = 0; n < 8; ++n) {
                const float xv = xw[wv][n][c];
                acc[n].x = fmaf(xv, w.x, acc[n].x);
                acc[n].y = fmaf(xv, w.y, acc[n].y);
                acc[n].z = fmaf(xv, w.z, acc[n].z);
                acc[n].w = fmaf(xv, w.w, acc[n].w);
            }
        }
        #pragma unroll
        for (int n = 0; n < 8; ++n) {
            acc[n].x += __shfl_xor(acc[n].x, 32);
            acc[n].y += __shfl_xor(acc[n].y, 32);
            acc[n].z += __shfl_xor(acc[n].z, 32);
            acc[n].w += __shfl_xor(acc[n].w, 32);
        }
        #pragma unroll
        for (int r = 0; r < 4; ++r) {
            const int n = half * 4 + r;
            float4 a = acc[n];
            a.x = a.x / (1.0f + __expf(-a.x));
            a.y = a.y / (1.0f + __expf(-a.y));
            a.z = a.z / (1.0f + __expf(-a.z));
            a.w = a.w / (1.0f + __expf(-a.w));
            *(float4*)&hh[wv][n][q * 4] = a;
        }
    }
    __syncthreads();

    // --- Phase 2: phi = h @ w2t + b2, three 128-wide segment passes ---
    #pragma unroll 1
    for (int sg = 0; sg < 3; ++sg) {
        float4 acc[8];
        const float4 bia = ((const float4*)(b2 + 128 * sg))[q];
        #pragma unroll
        for (int n = 0; n < 8; ++n)
            acc[n] = (half == 0) ? bia : make_float4(0.f, 0.f, 0.f, 0.f);

        #pragma unroll 4
        for (int it = 0; it < 64; ++it) {
            const int c = 2 * it + half;
            const float4 w = *(const float4*)(w2t + (size_t)c * 384 + 128 * sg + 4 * q);
            #pragma unroll
            for (int n = 0; n < 8; ++n) {
                const float hv = hh[wv][n][c];
                acc[n].x = fmaf(hv, w.x, acc[n].x);
                acc[n].y = fmaf(hv, w.y, acc[n].y);
                acc[n].z = fmaf(hv, w.z, acc[n].z);
                acc[n].w = fmaf(hv, w.w, acc[n].w);
            }
        }
        #pragma unroll
        for (int n = 0; n < 8; ++n) {
            acc[n].x += __shfl_xor(acc[n].x, 32);
            acc[n].y += __shfl_xor(acc[n].y, 32);
            acc[n].z += __shfl_xor(acc[n].z, 32);
            acc[n].w += __shfl_xor(acc[n].w, 32);
        }
        #pragma unroll
        for (int r = 0; r < 4; ++r) {
            const int n = half * 4 + r;
            uint2 pk;
            pk.x = pack2bf(acc[n].x, acc[n].y);
            pk.y = pack2bf(acc[n].z, acc[n].w);
            // group q, uint offset 2*sg within the 12-uint group
            *(uint2*)(rec + (size_t)(nbase + n) * 384 + q * 12 + 2 * sg) = pk;
        }
    }
}

// ---------------------------------------------------------------------------
// Gather kernel: one wave per node, TWO edges per iteration (half-wave split),
// software-pipelined: data loads issued 2 iterations ahead, bucket entries 3.
// ---------------------------------------------------------------------------
struct EdgeRegs {
    uint4 u0, u1, u2;       // rec slice: 48 B for this lane's channel group
    float4 f0, f1, f2;      // rbf slices: m_s, m_vv, m_vs channels
};

__device__ __forceinline__ void issue_loads(const unsigned int* __restrict__ rec,
                                            const float* __restrict__ rbf,
                                            int4 ent, int q, EdgeRegs& R) {
    const uint4* rj = (const uint4*)(rec + (size_t)ent.y * 384) + 3 * q;
    R.u0 = rj[0];
    R.u1 = rj[1];
    R.u2 = rj[2];
    const float* rb = rbf + (size_t)ent.x * 384;
    R.f0 = ntload4(rb + 4 * q);
    R.f1 = ntload4(rb + 128 + 4 * q);
    R.f2 = ntload4(rb + 256 + 4 * q);
}

__device__ __forceinline__ void edge_accum(int4 ent, const EdgeRegs& R,
                                           float4& acc_s, float4& av0,
                                           float4& av1, float4& av2) {
    __half2 h01 = *reinterpret_cast<const __half2*>(&ent.z);
    float2 ev01 = __half22float2(h01);
    unsigned short h2u = (unsigned short)(ent.w & 0xFFFF);
    float ev2 = __half2float(*reinterpret_cast<const __half*>(&h2u));

    float4 ps = make_float4(bf_lo(R.u0.x), bf_hi(R.u0.x), bf_lo(R.u0.y), bf_hi(R.u0.y));
    acc_s.x = fmaf(ps.x, R.f0.x, acc_s.x);
    acc_s.y = fmaf(ps.y, R.f0.y, acc_s.y);
    acc_s.z = fmaf(ps.z, R.f0.z, acc_s.z);
    acc_s.w = fmaf(ps.w, R.f0.w, acc_s.w);

    float4 pv = make_float4(bf_lo(R.u0.z), bf_hi(R.u0.z), bf_lo(R.u0.w), bf_hi(R.u0.w));
    float4 pw = make_float4(bf_lo(R.u1.x), bf_hi(R.u1.x), bf_lo(R.u1.y), bf_hi(R.u1.y));
    float4 mvv = make_float4(pv.x * R.f1.x, pv.y * R.f1.y, pv.z * R.f1.z, pv.w * R.f1.w);
    float4 mvs = make_float4(pw.x * R.f2.x, pw.y * R.f2.y, pw.z * R.f2.z, pw.w * R.f2.w);

    float4 v0 = make_float4(bf_lo(R.u1.z), bf_hi(R.u1.z), bf_lo(R.u1.w), bf_hi(R.u1.w));
    float4 v1 = make_float4(bf_lo(R.u2.x), bf_hi(R.u2.x), bf_lo(R.u2.y), bf_hi(R.u2.y));
    float4 v2 = make_float4(bf_lo(R.u2.z), bf_hi(R.u2.z), bf_lo(R.u2.w), bf_hi(R.u2.w));

    av0.x = fmaf(v0.x, mvv.x, fmaf(ev01.x, mvs.x, av0.x));
    av0.y = fmaf(v0.y, mvv.y, fmaf(ev01.x, mvs.y, av0.y));
    av0.z = fmaf(v0.z, mvv.z, fmaf(ev01.x, mvs.z, av0.z));
    av0.w = fmaf(v0.w, mvv.w, fmaf(ev01.x, mvs.w, av0.w));
    av1.x = fmaf(v1.x, mvv.x, fmaf(ev01.y, mvs.x, av1.x));
    av1.y = fmaf(v1.y, mvv.y, fmaf(ev01.y, mvs.y, av1.y));
    av1.z = fmaf(v1.z, mvv.z, fmaf(ev01.y, mvs.z, av1.z));
    av1.w = fmaf(v1.w, mvv.w, fmaf(ev01.y, mvs.w, av1.w));
    av2.x = fmaf(v2.x, mvv.x, fmaf(ev2, mvs.x, av2.x));
    av2.y = fmaf(v2.y, mvv.y, fmaf(ev2, mvs.y, av2.y));
    av2.z = fmaf(v2.z, mvv.z, fmaf(ev2, mvs.z, av2.z));
    av2.w = fmaf(v2.w, mvv.w, fmaf(ev2, mvs.w, av2.w));
}

__global__ __launch_bounds__(256) void gather_kernel(const float* __restrict__ s,
                                                     const float* __restrict__ v,
                                                     const unsigned int* __restrict__ rec,
                                                     const float* __restrict__ rbf,
                                                     const int* __restrict__ offsets,
                                                     const int* __restrict__ counts,
                                                     const int4* __restrict__ bucket,
                                                     float* __restrict__ out_s,
                                                     float* __restrict__ out_v) {
    const int t = threadIdx.x;
    const int n = blockIdx.x * 4 + (t >> 6);     // 2500 blocks * 4 waves = NN
    const int l = t & 63;
    const int half = l >> 5;
    const int q = l & 31;

    float4 acc_s = make_float4(0.f, 0.f, 0.f, 0.f);
    float4 av0 = acc_s, av1 = acc_s, av2 = acc_s;

    const int beg = offsets[n];
    const int deg = counts[n];
    const int npair = deg >> 1;
    const int4* bk = bucket + beg;

    // Pipeline state:
    //   eA/RA = edge-pair p (data resident or in flight)
    //   eB/RB = edge-pair p+1 (data in flight)
    //   eC    = bucket entry for p+2 (address prefetch)
    int4 eA = make_int4(0, 0, 0, 0), eB = eA, eC = eA;
    EdgeRegs RA, RB;
    if (npair > 0) eA = bk[half];
    if (npair > 1) eB = bk[2 + half];
    if (npair > 0) issue_loads(rec, rbf, eA, q, RA);
    if (npair > 1) issue_loads(rec, rbf, eB, q, RB);
    if (npair > 2) eC = bk[4 + half];

    #pragma unroll 2
    for (int p = 0; p < npair; ++p) {
        edge_accum(eA, RA, acc_s, av0, av1, av2);
        eA = eB; RA = RB; eB = eC;
        if (p + 2 < npair) issue_loads(rec, rbf, eB, q, RB);   // data for p+2
        if (p + 3 < npair) eC = bk[2 * (p + 3) + half];        // entry for p+3
    }

    // Tail edge (odd degree): lanes of half 0 only.
    if ((deg & 1) && half == 0) {
        int4 te = bk[deg - 1];
        EdgeRegs RT;
        issue_loads(rec, rbf, te, q, RT);
        edge_accum(te, RT, acc_s, av0, av1, av2);
    }

    // Cross-half reduction: lanes q and q+32 hold the same channels.
    acc_s.x += __shfl_xor(acc_s.x, 32);
    acc_s.y += __shfl_xor(acc_s.y, 32);
    acc_s.z += __shfl_xor(acc_s.z, 32);
    acc_s.w += __shfl_xor(acc_s.w, 32);
    av0.x += __shfl_xor(av0.x, 32);
    av0.y += __shfl_xor(av0.y, 32);
    av0.z += __shfl_xor(av0.z, 32);
    av0.w += __shfl_xor(av0.w, 32);
    av1.x += __shfl_xor(av1.x, 32);
    av1.y += __shfl_xor(av1.y, 32);
    av1.z += __shfl_xor(av1.z, 32);
    av1.w += __shfl_xor(av1.w, 32);
    av2.x += __shfl_xor(av2.x, 32);
    av2.y += __shfl_xor(av2.y, 32);
    av2.z += __shfl_xor(av2.z, 32);
    av2.w += __shfl_xor(av2.w, 32);

    // Epilogue: out = fp32 input + SCALE * acc. Rows split across halves.
    const size_t nb = (size_t)n;
    if (half == 0) {
        float4 sv = ((const float4*)(s + nb * CH))[q];
        ((float4*)(out_s + nb * CH))[q] =
            make_float4(sv.x + SCALE_F * acc_s.x, sv.y + SCALE_F * acc_s.y,
                        sv.z + SCALE_F * acc_s.z, sv.w + SCALE_F * acc_s.w);
        float4 w0 = ((const float4*)(v + nb * 384))[q];
        ((float4*)(out_v + nb * 384))[q] =
            make_float4(w0.x + SCALE_F * av0.x, w0.y + SCALE_F * av0.y,
                        w0.z + SCALE_F * av0.z, w0.w + SCALE_F * av0.w);
    } else {
        float4 w1 = ((const float4*)(v + nb * 384 + 128))[q];
        ((float4*)(out_v + nb * 384 + 128))[q] =
            make_float4(w1.x + SCALE_F * av1.x, w1.y + SCALE_F * av1.y,
                        w1.z + SCALE_F * av1.z, w1.w + SCALE_F * av1.w);
        float4 w2 = ((const float4*)(v + nb * 384 + 256))[q];
        ((float4*)(out_v + nb * 384 + 256))[q] =
            make_float4(w2.x + SCALE_F * av2.x, w2.y + SCALE_F * av2.y,
                        w2.z + SCALE_F * av2.z, w2.w + SCALE_F * av2.w);
    }
}

// ---------------------------------------------------------------------------
extern "C" void kernel_launch(void* const* d_in, const int* in_sizes, int n_in,
                              void* d_out, int out_size, void* d_ws, size_t ws_size,
                              hipStream_t stream) {
    const float* s    = (const float*)d_in[0];
    const float* v    = (const float*)d_in[1];
    const int*   ei   = (const int*)d_in[2];
    const float* rbf  = (const float*)d_in[3];
    const float* ev   = (const float*)d_in[4];
    const float* w1   = (const float*)d_in[5];
    const float* b1   = (const float*)d_in[6];
    const float* w2   = (const float*)d_in[7];
    const float* b2   = (const float*)d_in[8];
    const float* rmsw = (const float*)d_in[9];

    float* out   = (float*)d_out;
    float* out_s = out;                       // [NN,1,CH]
    float* out_v = out + (size_t)NN * CH;     // [NN,3,CH]

    // Workspace layout (all 16B-aligned)
    char* ws = (char*)d_ws;
    unsigned int* rec = (unsigned int*)ws;     ws += (size_t)NN * 384 * sizeof(unsigned int); // 15.36 MB
    int* i64flag = (int*)ws;                   ws += 64;
    int* counts  = (int*)ws;                   ws += (size_t)NN * sizeof(int);
    int* offsets = (int*)ws;                   ws += (size_t)NN * sizeof(int);
    int* cursor  = (int*)ws;                   ws += (size_t)NN * sizeof(int) + 48; // re-align 16B
    int4* bucket = (int4*)ws;                  ws += (size_t)NE * sizeof(int4);     // 2.56 MB
    float* w1t   = (float*)ws;                 ws += (size_t)128 * 128 * sizeof(float); // 64 KB
    float* w2t   = (float*)ws;                 // 192 KB

    detect_zero_kernel<<<(NN + 255) / 256, 256, 0, stream>>>(ei, i64flag, counts);
    transpose_w_kernel<<<256, 256, 0, stream>>>(w1, w2, w1t, w2t);
    count_kernel<<<(NE + 255) / 256, 256, 0, stream>>>(ei, i64flag, counts);
    scan_kernel<<<1, 1024, 0, stream>>>(counts, offsets, cursor);
    bucket_kernel<<<(NE + 255) / 256, 256, 0, stream>>>(ei, i64flag, ev, cursor, bucket);
    phi_kernel<<<NN / 16, 128, 0, stream>>>(s, v, w1t, b1, w2t, b2, rmsw, rec);
    gather_kernel<<<NN / 4, 256, 0, stream>>>(s, v, rec, rbf, offsets, counts, bucket,
                                              out_s, out_v);
}